// Round 1
// baseline (49771.030 us; speedup 1.0000x reference)
//
#include <hip/hip_runtime.h>
#include <hip/hip_bf16.h>

#define NTOK 49
#define DIMC 384
#define NH 12
#define HD 32
#define QSCALE 0.17677669529663687f   // 32^-0.5

// LDS float offsets (all multiples of 4 for float4 casts)
#define XS_OFF   0          // 49*384 = 18816
#define QS_OFF   18816      // 49*36  = 1764 (stride 36: 16B-aligned rows, odd /4 -> conflict-free)
#define KS_OFF   20580      // 1764
#define VS_OFF   22344      // 1764
#define SS_OFF   24108      // 49*49 = 2401, pad to 2404
#define WS_OFF   26512      // max(qkv tile 96*68=6528, proj slice 384*36=13824) = 13824
#define LDS_FLOATS 40336    // 161344 bytes <= 160 KiB

__device__ __forceinline__ int cof(int p) { return 13 * (p / 7) + (p % 7); }
__device__ __forceinline__ float dot4(float4 a, float4 b) {
    return a.x*b.x + a.y*b.y + a.z*b.z + a.w*b.w;
}

__global__ __launch_bounds__(512, 1)
void winattn_f32_kernel(const float* __restrict__ x, const float* __restrict__ mask,
                        const float* __restrict__ qkv_w, const float* __restrict__ qkv_b,
                        const float* __restrict__ proj_w, const float* __restrict__ proj_b,
                        const float* __restrict__ bias_table, float* __restrict__ out)
{
    __shared__ float lds[LDS_FLOATS];
    float* xs  = lds + XS_OFF;
    float* qs  = lds + QS_OFF;
    float* ks  = lds + KS_OFF;
    float* vs  = lds + VS_OFF;
    float* ss  = lds + SS_OFF;
    float* wsc = lds + WS_OFF;

    const int tid = threadIdx.x;
    const int win = blockIdx.x;
    const size_t xbase = (size_t)win * (NTOK * DIMC);

    // ---- load x window into LDS (coalesced float4) ----
    {
        const float4* xg = (const float4*)(x + xbase);
        float4* xl = (float4*)xs;
        for (int f = tid; f < NTOK * DIMC / 4; f += 512) xl[f] = xg[f];
    }

    float acc[39];
    #pragma unroll
    for (int k = 0; k < 39; ++k) acc[k] = 0.f;

    const int i0 = tid / 48;   // qkv mapping (active: tid < 480)
    const int r2 = tid % 48;
    const int cg = tid & 127;  // proj mapping: c = 3*cg + dc
    const int ig = tid >> 7;   // proj mapping: i = ig + 4*t
    const float* maskp = mask + (size_t)(win & 63) * (NTOK * NTOK);

    __syncthreads();

    for (int h = 0; h < NH; ++h) {
        // ================= QKV projection for head h =================
        // y[i][r], r in [0,96): r<32 -> q col r, r<64 -> k col r-32, else v col r-64
        float prt[5][2];
        #pragma unroll
        for (int t = 0; t < 5; ++t) { prt[t][0] = 0.f; prt[t][1] = 0.f; }

        for (int c0 = 0; c0 < DIMC; c0 += 64) {
            __syncthreads();   // protects wsc reuse (prev head's proj reads / prev tile reads)
            // stage W tile wt[96][68]
            for (int f = tid; f < 96 * 64; f += 512) {
                int r = f >> 6, cc = f & 63;
                int grow = (r < 32) ? (h*32 + r)
                         : (r < 64) ? (384 + h*32 + (r - 32))
                                    : (768 + h*32 + (r - 64));
                wsc[r*68 + cc] = qkv_w[(size_t)grow * DIMC + c0 + cc];
            }
            __syncthreads();
            if (tid < 480) {
                const float4* wt4 = (const float4*)wsc;
                const float4* xs4 = (const float4*)xs;
                const int ra = r2, rb = r2 + 48;
                for (int cc4 = 0; cc4 < 16; ++cc4) {
                    float4 wa = wt4[ra*17 + cc4];
                    float4 wb = wt4[rb*17 + cc4];
                    #pragma unroll
                    for (int t = 0; t < 5; ++t) {
                        int i = i0 + 10*t;
                        if (i < NTOK) {
                            float4 xv = xs4[i*96 + (c0 >> 2) + cc4];
                            prt[t][0] += dot4(xv, wa);
                            prt[t][1] += dot4(xv, wb);
                        }
                    }
                }
            }
        }
        __syncthreads();
        // write q (pre-scaled), k, v to LDS
        if (tid < 480) {
            #pragma unroll
            for (int s = 0; s < 2; ++s) {
                int r = (s == 0) ? r2 : (r2 + 48);
                int gb = (r < 32) ? (h*32 + r)
                       : (r < 64) ? (384 + h*32 + (r - 32))
                                  : (768 + h*32 + (r - 64));
                float bias = qkv_b[gb];
                #pragma unroll
                for (int t = 0; t < 5; ++t) {
                    int i = i0 + 10*t;
                    if (i < NTOK) {
                        float val = prt[t][s] + bias;
                        if (r < 32)      qs[i*36 + r]        = val * QSCALE;
                        else if (r < 64) ks[i*36 + (r - 32)] = val;
                        else             vs[i*36 + (r - 64)] = val;
                    }
                }
            }
        }
        __syncthreads();
        // ================= scores: q k^T + rel_bias + mask =================
        {
            const float4* qs4 = (const float4*)qs;
            const float4* ks4 = (const float4*)ks;
            for (int t = tid; t < NTOK * NTOK; t += 512) {
                int i = t / 49, m = t % 49;
                float s = 0.f;
                #pragma unroll
                for (int j4 = 0; j4 < 8; ++j4) s += dot4(qs4[i*9 + j4], ks4[m*9 + j4]);
                int idx = cof(i) + cof(48 - m);
                s += bias_table[idx * NH + h] + maskp[t];
                ss[t] = s;
            }
        }
        __syncthreads();
        // ================= softmax per row (wave-parallel) =================
        {
            int wv = tid >> 6, ln = tid & 63;
            for (int row = wv; row < NTOK; row += 8) {
                float v = (ln < NTOK) ? ss[row*49 + ln] : -3.0e38f;
                float mx = v;
                #pragma unroll
                for (int off = 32; off >= 1; off >>= 1) mx = fmaxf(mx, __shfl_xor(mx, off));
                float e = (ln < NTOK) ? __expf(v - mx) : 0.f;
                float sm = e;
                #pragma unroll
                for (int off = 32; off >= 1; off >>= 1) sm += __shfl_xor(sm, off);
                if (ln < NTOK) ss[row*49 + ln] = e / sm;
            }
        }
        __syncthreads();
        // ================= av = P @ V (into qs cols 0..31) =================
        for (int t = tid; t < NTOK * HD; t += 512) {
            int i = t >> 5, j = t & 31;
            float a = 0.f;
            for (int m = 0; m < NTOK; ++m) a += ss[i*49 + m] * vs[m*36 + j];
            qs[i*36 + j] = a;
        }
        __syncthreads();
        // ================= stage proj slice pw[384][36] =================
        for (int f = tid; f < DIMC * HD; f += 512) {
            int c = f >> 5, j = f & 31;
            wsc[c*36 + j] = proj_w[(size_t)c * DIMC + h*32 + j];
        }
        __syncthreads();
        // ================= proj accumulate into registers =================
        {
            const float4* av4 = (const float4*)qs;
            const float4* pw4 = (const float4*)wsc;
            #pragma unroll
            for (int j4 = 0; j4 < 8; ++j4) {
                float4 a[13];
                #pragma unroll
                for (int t = 0; t < 13; ++t) {
                    int i = ig + 4*t;
                    a[t] = (i < NTOK) ? av4[i*9 + j4] : make_float4(0.f, 0.f, 0.f, 0.f);
                }
                #pragma unroll
                for (int dc = 0; dc < 3; ++dc) {
                    int c = cg*3 + dc;
                    float4 p4 = pw4[c*9 + j4];
                    #pragma unroll
                    for (int t = 0; t < 13; ++t)
                        acc[t*3 + dc] += dot4(a[t], p4);
                }
            }
        }
        // next head's c0-loop opens with __syncthreads(), protecting wsc/qs reuse
    }

    // ================= epilogue: + proj_b, store =================
    {
        float* op = out + xbase;
        #pragma unroll
        for (int t = 0; t < 13; ++t) {
            int i = ig + 4*t;
            if (i < NTOK) {
                #pragma unroll
                for (int dc = 0; dc < 3; ++dc) {
                    int c = cg*3 + dc;
                    op[i*DIMC + c] = acc[t*3 + dc] + proj_b[c];
                }
            }
        }
    }
}

extern "C" void kernel_launch(void* const* d_in, const int* in_sizes, int n_in,
                              void* d_out, int out_size, void* d_ws, size_t ws_size,
                              hipStream_t stream) {
    const float* x          = (const float*)d_in[0];
    const float* mask       = (const float*)d_in[1];
    const float* qkv_w      = (const float*)d_in[2];
    const float* qkv_b      = (const float*)d_in[3];
    const float* proj_w     = (const float*)d_in[4];
    const float* proj_b     = (const float*)d_in[5];
    const float* bias_table = (const float*)d_in[6];
    float* out = (float*)d_out;

    winattn_f32_kernel<<<4096, 512, 0, stream>>>(x, mask, qkv_w, qkv_b,
                                                 proj_w, proj_b, bias_table, out);
}

// Round 2
// 3110.708 us; speedup vs baseline: 15.9999x; 15.9999x over previous
//
#include <hip/hip_runtime.h>
#include <hip/hip_bf16.h>

#define NTOK 49
#define DIMC 384
#define NH 12
#define QSCALE 0.17677669529663687f

typedef __attribute__((ext_vector_type(8))) short short8;
typedef __attribute__((ext_vector_type(4))) float f32x4;

#define PAD 88
// LDS layout (short elements)
#define KS_OFF 0        // [64][88]
#define VT_OFF 5632     // [32][88]
#define AV_OFF 8448     // [64][88]
#define QS_OFF 14080    // 4 x [16][88] wave-private
#define PS_OFF 19712    // 4 x [16][88] wave-private
#define SL_TOT 25344    // 50688 bytes

__device__ __forceinline__ short f2bf(float f) {
    __bf16 h = (__bf16)f;
    return __builtin_bit_cast(short, h);
}
__device__ __forceinline__ int cof(int p) { return 13 * (p / 7) + (p % 7); }

template<bool WPREP>
__device__ __forceinline__ short8 load_bfrag(const short* __restrict__ wb,
                                             const float* __restrict__ wf,
                                             int row, int koff) {
    if constexpr (WPREP) {
        return *(const short8*)(wb + row * DIMC + koff);
    } else {
        const float* p = wf + row * DIMC + koff;
        float4 a = *(const float4*)p;
        float4 b = *(const float4*)(p + 4);
        short8 r;
        r[0]=f2bf(a.x); r[1]=f2bf(a.y); r[2]=f2bf(a.z); r[3]=f2bf(a.w);
        r[4]=f2bf(b.x); r[5]=f2bf(b.y); r[6]=f2bf(b.z); r[7]=f2bf(b.w);
        return r;
    }
}

__global__ void prep_weights(const float* __restrict__ qw, const float* __restrict__ pw,
                             short* __restrict__ wqb, short* __restrict__ wpb) {
    const int NQ = 1152 * DIMC, NP = DIMC * DIMC;
    for (int i = blockIdx.x * blockDim.x + threadIdx.x; i < NQ + NP;
         i += gridDim.x * blockDim.x) {
        if (i < NQ) wqb[i] = f2bf(qw[i]);
        else        wpb[i - NQ] = f2bf(pw[i - NQ]);
    }
}

template<bool WPREP>
__global__ __launch_bounds__(256, 2)
void winattn_mfma(const float* __restrict__ x, const float* __restrict__ mask,
                  const float* __restrict__ qkv_w, const float* __restrict__ qkv_b,
                  const float* __restrict__ proj_w, const float* __restrict__ proj_b,
                  const float* __restrict__ bias_table,
                  const short* __restrict__ wqb, const short* __restrict__ wpb,
                  float* __restrict__ out)
{
    __shared__ short SL[SL_TOT];

    const int tid  = threadIdx.x;
    const int wv   = tid >> 6;
    const int lane = tid & 63;
    const int l15  = lane & 15;
    const int l4   = lane >> 4;
    const int win  = blockIdx.x;
    const int xbase = win * (NTOK * DIMC);

    // ---- x A-fragments in registers: 12 k-steps x short8 (row = wv*16 + l15) ----
    short8 xf[12];
    {
        const int row = wv * 16 + l15;
        const bool valid = row < NTOK;
        const float* xr = x + xbase + row * DIMC;
        #pragma unroll
        for (int ks = 0; ks < 12; ++ks) {
            short8 r;
            if (valid) {
                float4 a = *(const float4*)(xr + ks * 32 + l4 * 8);
                float4 b = *(const float4*)(xr + ks * 32 + l4 * 8 + 4);
                r[0]=f2bf(a.x); r[1]=f2bf(a.y); r[2]=f2bf(a.z); r[3]=f2bf(a.w);
                r[4]=f2bf(b.x); r[5]=f2bf(b.y); r[6]=f2bf(b.z); r[7]=f2bf(b.w);
            } else {
                r = (short8)0;
            }
            xf[ks] = r;
        }
    }

    // ---- mask in regs + rel-idx precompute (C-layout: row = wv*16 + l4*4 + reg, col m = t*16 + l15) ----
    float mv[4][4];
    int   cofi[4], cofm[4];
    float negm[4];
    {
        const float* maskp = mask + (win & 63) * (NTOK * NTOK);
        #pragma unroll
        for (int t = 0; t < 4; ++t) {
            int m = t * 16 + l15;
            negm[t] = (m < NTOK) ? 0.f : -1e30f;
            int mm = m < NTOK ? m : 48;
            cofm[t] = cof(48 - mm);
            #pragma unroll
            for (int reg = 0; reg < 4; ++reg) {
                int i = wv * 16 + l4 * 4 + reg;
                mv[t][reg] = (i < NTOK && m < NTOK) ? maskp[i * NTOK + m] : 0.f;
            }
        }
        #pragma unroll
        for (int reg = 0; reg < 4; ++reg) {
            int i = wv * 16 + l4 * 4 + reg;
            cofi[reg] = cof(i < NTOK ? i : 48);
        }
    }

    f32x4 pacc[24];
    #pragma unroll
    for (int t = 0; t < 24; ++t) pacc[t] = (f32x4){0.f, 0.f, 0.f, 0.f};

    const f32x4 zf = (f32x4){0.f, 0.f, 0.f, 0.f};

    #pragma unroll 1
    for (int h = 0; h < NH; ++h) {
        // ================= phase A: qkv GEMM (B direct from global bf16) =================
        f32x4 qa[6];
        #pragma unroll
        for (int nt = 0; nt < 6; ++nt) qa[nt] = zf;

        #pragma unroll
        for (int nt = 0; nt < 6; ++nt) {
            const int grow = (nt >> 1) * DIMC + h * 32 + (nt & 1) * 16 + l15;
            #pragma unroll
            for (int ks = 0; ks < 12; ++ks) {
                short8 b = load_bfrag<WPREP>(wqb, qkv_w, grow, ks * 32 + l4 * 8);
                qa[nt] = __builtin_amdgcn_mfma_f32_16x16x32_bf16(xf[ks], b, qa[nt], 0, 0, 0);
            }
        }
        // epilogue: +bias, scale q, write q->QS(own), k->KS, v->VT (bf16)
        #pragma unroll
        for (int nt = 0; nt < 6; ++nt) {
            const int sub = nt >> 1;                 // 0=q 1=k 2=v
            const int colw = (nt & 1) * 16 + l15;    // 0..31 within head
            const float bias = qkv_b[sub * DIMC + h * 32 + colw];
            #pragma unroll
            for (int reg = 0; reg < 4; ++reg) {
                const int rl = l4 * 4 + reg;         // 0..15 within stripe
                const int tokg = wv * 16 + rl;
                float val = qa[nt][reg] + bias;
                if (sub == 0) {
                    SL[QS_OFF + wv * 1408 + rl * PAD + colw] = f2bf(val * QSCALE);
                } else if (sub == 1) {
                    SL[KS_OFF + tokg * PAD + colw] = f2bf(val);
                } else {
                    SL[VT_OFF + colw * PAD + tokg] = f2bf(val);
                }
            }
        }
        __syncthreads();

        // ================= phase B: QK^T =================
        short8 aq = *(const short8*)&SL[QS_OFF + wv * 1408 + l15 * PAD + l4 * 8];
        f32x4 sc[4];
        #pragma unroll
        for (int t = 0; t < 4; ++t) {
            short8 bk = *(const short8*)&SL[KS_OFF + (t * 16 + l15) * PAD + l4 * 8];
            sc[t] = __builtin_amdgcn_mfma_f32_16x16x32_bf16(aq, bk, zf, 0, 0, 0);
        }
        // logits + bias + mask, softmax over 64 cols (t in-reg, l15 cross-lane)
        float p[4][4];
        #pragma unroll
        for (int t = 0; t < 4; ++t) {
            #pragma unroll
            for (int reg = 0; reg < 4; ++reg) {
                float bt = bias_table[(cofi[reg] + cofm[t]) * NH + h];
                p[t][reg] = sc[t][reg] + mv[t][reg] + bt + negm[t];
            }
        }
        #pragma unroll
        for (int reg = 0; reg < 4; ++reg) {
            float mx = fmaxf(fmaxf(p[0][reg], p[1][reg]), fmaxf(p[2][reg], p[3][reg]));
            #pragma unroll
            for (int off = 8; off >= 1; off >>= 1) mx = fmaxf(mx, __shfl_xor(mx, off, 64));
            float s0 = 0.f;
            #pragma unroll
            for (int t = 0; t < 4; ++t) { p[t][reg] = __expf(p[t][reg] - mx); s0 += p[t][reg]; }
            #pragma unroll
            for (int off = 8; off >= 1; off >>= 1) s0 += __shfl_xor(s0, off, 64);
            float rs = 1.f / s0;
            #pragma unroll
            for (int t = 0; t < 4; ++t) p[t][reg] *= rs;
        }
        // P -> wave-private LDS (bf16), row-major [16][PAD]
        #pragma unroll
        for (int t = 0; t < 4; ++t)
            #pragma unroll
            for (int reg = 0; reg < 4; ++reg)
                SL[PS_OFF + wv * 1408 + (l4 * 4 + reg) * PAD + t * 16 + l15] = f2bf(p[t][reg]);

        // ================= PV =================
        f32x4 av[2];
        av[0] = zf; av[1] = zf;
        #pragma unroll
        for (int kst = 0; kst < 2; ++kst) {
            short8 pa = *(const short8*)&SL[PS_OFF + wv * 1408 + l15 * PAD + kst * 32 + l4 * 8];
            #pragma unroll
            for (int dt = 0; dt < 2; ++dt) {
                short8 bv = *(const short8*)&SL[VT_OFF + (dt * 16 + l15) * PAD + kst * 32 + l4 * 8];
                av[dt] = __builtin_amdgcn_mfma_f32_16x16x32_bf16(pa, bv, av[dt], 0, 0, 0);
            }
        }
        #pragma unroll
        for (int dt = 0; dt < 2; ++dt)
            #pragma unroll
            for (int reg = 0; reg < 4; ++reg)
                SL[AV_OFF + (wv * 16 + l4 * 4 + reg) * PAD + dt * 16 + l15] = f2bf(av[dt][reg]);

        // ================= proj partial (K = this head's 32 dims) =================
        short8 aa = *(const short8*)&SL[AV_OFF + (wv * 16 + l15) * PAD + l4 * 8];
        #pragma unroll
        for (int nt = 0; nt < 24; ++nt) {
            short8 bp = load_bfrag<WPREP>(wpb, proj_w, nt * 16 + l15, h * 32 + l4 * 8);
            pacc[nt] = __builtin_amdgcn_mfma_f32_16x16x32_bf16(aa, bp, pacc[nt], 0, 0, 0);
        }
        __syncthreads();
    }

    // ================= epilogue: +proj_b, store =================
    {
        float* op = out + xbase;
        #pragma unroll
        for (int nt = 0; nt < 24; ++nt) {
            const float pb = proj_b[nt * 16 + l15];
            #pragma unroll
            for (int reg = 0; reg < 4; ++reg) {
                const int i = wv * 16 + l4 * 4 + reg;
                if (i < NTOK) op[i * DIMC + nt * 16 + l15] = pacc[nt][reg] + pb;
            }
        }
    }
}

extern "C" void kernel_launch(void* const* d_in, const int* in_sizes, int n_in,
                              void* d_out, int out_size, void* d_ws, size_t ws_size,
                              hipStream_t stream) {
    const float* x          = (const float*)d_in[0];
    const float* mask       = (const float*)d_in[1];
    const float* qkv_w      = (const float*)d_in[2];
    const float* qkv_b      = (const float*)d_in[3];
    const float* proj_w     = (const float*)d_in[4];
    const float* proj_b     = (const float*)d_in[5];
    const float* bias_table = (const float*)d_in[6];
    float* out = (float*)d_out;

    const size_t need = (size_t)(1152 * DIMC + DIMC * DIMC) * 2;
    if (ws_size >= need) {
        short* wqb = (short*)d_ws;
        short* wpb = wqb + 1152 * DIMC;
        prep_weights<<<512, 256, 0, stream>>>(qkv_w, proj_w, wqb, wpb);
        winattn_mfma<true><<<4096, 256, 0, stream>>>(x, mask, qkv_w, qkv_b, proj_w,
                                                     proj_b, bias_table, wqb, wpb, out);
    } else {
        winattn_mfma<false><<<4096, 256, 0, stream>>>(x, mask, qkv_w, qkv_b, proj_w,
                                                      proj_b, bias_table, nullptr, nullptr, out);
    }
}

// Round 3
// 1111.974 us; speedup vs baseline: 44.7592x; 2.7975x over previous
//
#include <hip/hip_runtime.h>
#include <hip/hip_bf16.h>

#define NTOK 49
#define DIMC 384
#define NH 12
#define QSCALE 0.17677669529663687f

typedef __attribute__((ext_vector_type(8))) short short8;
typedef __attribute__((ext_vector_type(4))) float f32x4;

// LDS layout (short elements)
#define QKV_ST  0        // 2 chunk buffers x 12 frags x 512 = 12288
#define PROJ_ST 12288    // 24 frags x 512 = 12288
#define QS_OFF  24576    // [64][40] = 2560
#define KS_OFF  27136    // [64][40] = 2560
#define VT_OFF  29696    // [32][72] = 2304
#define PS_OFF  32000    // [64][72] = 4608
#define AV_OFF  36608    // [64][40] = 2560
#define SL_TOT  39168    // 78336 bytes -> 2 blocks/CU

#define NQFRAG (NH * 6 * 12)   // 864 qkv fragments
#define NPFRAG (NH * 24)       // 288 proj fragments

__device__ __forceinline__ short f2bf(float f) {
    __bf16 h = (__bf16)f;
    return __builtin_bit_cast(short, h);
}
__device__ __forceinline__ int cof(int p) { return 13 * (p / 7) + (p % 7); }

typedef unsigned int u32;
__device__ __forceinline__ void gld_lds16(const void* g, void* l) {
    __builtin_amdgcn_global_load_lds(
        (const __attribute__((address_space(1))) u32*)g,
        (__attribute__((address_space(3))) u32*)l, 16, 0, 0);
}

// fallback gather (fp32 source, uncoalesced — correctness path only)
__device__ __forceinline__ short8 gather_bf(const float* __restrict__ w, int row, int k0) {
    const float* p = w + row * DIMC + k0;
    float4 a = *(const float4*)p;
    float4 b = *(const float4*)(p + 4);
    short8 r;
    r[0]=f2bf(a.x); r[1]=f2bf(a.y); r[2]=f2bf(a.z); r[3]=f2bf(a.w);
    r[4]=f2bf(b.x); r[5]=f2bf(b.y); r[6]=f2bf(b.z); r[7]=f2bf(b.w);
    return r;
}

// -------- prep: fragment-tiled bf16 weights --------
// wqb: frag F = (h*6 + nt)*12 + ks ; element (F, lane, e) = qkv_w[grow][ks*32 + l4*8 + e]
//      grow = (nt>>1)*384 + h*32 + (nt&1)*16 + l15
// wpb: frag G = h*24 + nt ; element = proj_w[nt*16 + l15][h*32 + l4*8 + e]
__global__ void prep_weights(const float* __restrict__ qw, const float* __restrict__ pw,
                             short* __restrict__ wqb, short* __restrict__ wpb) {
    int gt = blockIdx.x * blockDim.x + threadIdx.x;
    if (gt < NQFRAG * 64) {
        int F = gt >> 6, lane = gt & 63;
        int h = F / 72, r = F % 72;
        int nt = r / 12, ks = r % 12;
        int l15 = lane & 15, l4 = lane >> 4;
        int grow = (nt >> 1) * DIMC + h * 32 + (nt & 1) * 16 + l15;
        const float* src = qw + grow * DIMC + ks * 32 + l4 * 8;
        short8 o;
        #pragma unroll
        for (int e = 0; e < 8; ++e) o[e] = f2bf(src[e]);
        *(short8*)(wqb + gt * 8) = o;
    } else if (gt < NQFRAG * 64 + NPFRAG * 64) {
        int t = gt - NQFRAG * 64;
        int G = t >> 6, lane = t & 63;
        int h = G / 24, nt = G % 24;
        int l15 = lane & 15, l4 = lane >> 4;
        const float* src = pw + (nt * 16 + l15) * DIMC + h * 32 + l4 * 8;
        short8 o;
        #pragma unroll
        for (int e = 0; e < 8; ++e) o[e] = f2bf(src[e]);
        *(short8*)(wpb + t * 8) = o;
    }
}

template<bool WPREP>
__global__ __launch_bounds__(256, 2)
void winattn_mfma(const float* __restrict__ x, const float* __restrict__ mask,
                  const float* __restrict__ qkv_w, const float* __restrict__ qkv_b,
                  const float* __restrict__ proj_w, const float* __restrict__ proj_b,
                  const float* __restrict__ bias_table,
                  const short* __restrict__ wqb, const short* __restrict__ wpb,
                  float* __restrict__ out)
{
    __shared__ short SL[SL_TOT] __attribute__((aligned(128)));

    const int tid  = threadIdx.x;
    const int wv   = tid >> 6;
    const int lane = tid & 63;
    const int l15  = lane & 15;
    const int l4   = lane >> 4;
    const int win  = blockIdx.x;
    const int xbase = win * (NTOK * DIMC);

    // ---- x A-fragments in registers: 12 k-steps x short8 ----
    short8 xf[12];
    {
        const int row = wv * 16 + l15;
        const bool valid = row < NTOK;
        const float* xr = x + xbase + row * DIMC;
        #pragma unroll
        for (int ks = 0; ks < 12; ++ks) {
            short8 r;
            if (valid) {
                float4 a = *(const float4*)(xr + ks * 32 + l4 * 8);
                float4 b = *(const float4*)(xr + ks * 32 + l4 * 8 + 4);
                r[0]=f2bf(a.x); r[1]=f2bf(a.y); r[2]=f2bf(a.z); r[3]=f2bf(a.w);
                r[4]=f2bf(b.x); r[5]=f2bf(b.y); r[6]=f2bf(b.z); r[7]=f2bf(b.w);
            } else {
                r = (short8)0;
            }
            xf[ks] = r;
        }
    }

    // ---- mask + rel-idx precompute ----
    float mv[4][4];
    int   cofi[4], cofm[4];
    float negm[4];
    {
        const float* maskp = mask + (win & 63) * (NTOK * NTOK);
        #pragma unroll
        for (int t = 0; t < 4; ++t) {
            int m = t * 16 + l15;
            negm[t] = (m < NTOK) ? 0.f : -1e30f;
            int mm = m < NTOK ? m : 48;
            cofm[t] = cof(48 - mm);
            #pragma unroll
            for (int reg = 0; reg < 4; ++reg) {
                int i = wv * 16 + l4 * 4 + reg;
                mv[t][reg] = (i < NTOK && m < NTOK) ? maskp[i * NTOK + m] : 0.f;
            }
        }
        #pragma unroll
        for (int reg = 0; reg < 4; ++reg) {
            int i = wv * 16 + l4 * 4 + reg;
            cofi[reg] = cof(i < NTOK ? i : 48);
        }
    }

    f32x4 pacc[24];
    #pragma unroll
    for (int t = 0; t < 24; ++t) pacc[t] = (f32x4){0.f, 0.f, 0.f, 0.f};
    const f32x4 zf = (f32x4){0.f, 0.f, 0.f, 0.f};

    // stage head-0 chunk-0 (frags j = wv*3..wv*3+2)
    if constexpr (WPREP) {
        #pragma unroll
        for (int t = 0; t < 3; ++t) {
            int j = wv * 3 + t;
            int F = (j >> 1) * 12 + (j & 1);
            gld_lds16(wqb + F * 512 + lane * 8, &SL[QKV_ST + j * 512]);
        }
    }
    __syncthreads();

    #pragma unroll 1
    for (int h = 0; h < NH; ++h) {
        // ================= phase A: qkv GEMM =================
        f32x4 qa[6];
        #pragma unroll
        for (int nt = 0; nt < 6; ++nt) qa[nt] = zf;

        if constexpr (WPREP) {
            #pragma unroll 1
            for (int c = 0; c < 6; ++c) {
                if (c < 5) {
                    #pragma unroll
                    for (int t = 0; t < 3; ++t) {
                        int j = wv * 3 + t;
                        int F = (h * 6 + (j >> 1)) * 12 + 2 * (c + 1) + (j & 1);
                        gld_lds16(wqb + F * 512 + lane * 8,
                                  &SL[QKV_ST + ((c + 1) & 1) * 6144 + j * 512]);
                    }
                }
                const short* buf = &SL[QKV_ST + (c & 1) * 6144];
                #pragma unroll
                for (int j = 0; j < 12; ++j) {
                    short8 b = *(const short8*)(buf + j * 512 + lane * 8);
                    qa[j >> 1] = __builtin_amdgcn_mfma_f32_16x16x32_bf16(
                        xf[2 * c + (j & 1)], b, qa[j >> 1], 0, 0, 0);
                }
                if (c < 5) __syncthreads();
            }
        } else {
            #pragma unroll
            for (int nt = 0; nt < 6; ++nt) {
                const int grow = (nt >> 1) * DIMC + h * 32 + (nt & 1) * 16 + l15;
                #pragma unroll
                for (int ks = 0; ks < 12; ++ks) {
                    short8 b = gather_bf(qkv_w, grow, ks * 32 + l4 * 8);
                    qa[nt] = __builtin_amdgcn_mfma_f32_16x16x32_bf16(xf[ks], b, qa[nt], 0, 0, 0);
                }
            }
        }

        // epilogue: +bias, scale q; q->QS, k->KS, v->VT (bf16)
        #pragma unroll
        for (int nt = 0; nt < 6; ++nt) {
            const int sub = nt >> 1;
            const int colw = (nt & 1) * 16 + l15;
            const float bias = qkv_b[sub * DIMC + h * 32 + colw];
            #pragma unroll
            for (int reg = 0; reg < 4; ++reg) {
                const int tokg = wv * 16 + l4 * 4 + reg;
                float val = qa[nt][reg] + bias;
                if (sub == 0)      SL[QS_OFF + tokg * 40 + colw] = f2bf(val * QSCALE);
                else if (sub == 1) SL[KS_OFF + tokg * 40 + colw] = f2bf(val);
                else               SL[VT_OFF + colw * 72 + tokg] = f2bf(val);
            }
        }
        __syncthreads();

        // stage proj frags for this head + next head's chunk-0 (hidden under attention)
        if constexpr (WPREP) {
            #pragma unroll
            for (int t = 0; t < 6; ++t) {
                int g = wv * 6 + t;
                gld_lds16(wpb + (h * 24 + g) * 512 + lane * 8, &SL[PROJ_ST + g * 512]);
            }
            if (h + 1 < NH) {
                #pragma unroll
                for (int t = 0; t < 3; ++t) {
                    int j = wv * 3 + t;
                    int F = ((h + 1) * 6 + (j >> 1)) * 12 + (j & 1);
                    gld_lds16(wqb + F * 512 + lane * 8, &SL[QKV_ST + j * 512]);
                }
            }
        }

        // ================= QK^T =================
        short8 aq = *(const short8*)&SL[QS_OFF + (wv * 16 + l15) * 40 + l4 * 8];
        f32x4 sc[4];
        #pragma unroll
        for (int t = 0; t < 4; ++t) {
            short8 bk = *(const short8*)&SL[KS_OFF + (t * 16 + l15) * 40 + l4 * 8];
            sc[t] = __builtin_amdgcn_mfma_f32_16x16x32_bf16(aq, bk, zf, 0, 0, 0);
        }
        // logits + rel-bias + mask, softmax
        float p[4][4];
        #pragma unroll
        for (int t = 0; t < 4; ++t) {
            #pragma unroll
            for (int reg = 0; reg < 4; ++reg) {
                float bt = bias_table[(cofi[reg] + cofm[t]) * NH + h];
                p[t][reg] = sc[t][reg] + mv[t][reg] + bt + negm[t];
            }
        }
        #pragma unroll
        for (int reg = 0; reg < 4; ++reg) {
            float mx = fmaxf(fmaxf(p[0][reg], p[1][reg]), fmaxf(p[2][reg], p[3][reg]));
            #pragma unroll
            for (int off = 8; off >= 1; off >>= 1) mx = fmaxf(mx, __shfl_xor(mx, off, 64));
            float s0 = 0.f;
            #pragma unroll
            for (int t = 0; t < 4; ++t) { p[t][reg] = __expf(p[t][reg] - mx); s0 += p[t][reg]; }
            #pragma unroll
            for (int off = 8; off >= 1; off >>= 1) s0 += __shfl_xor(s0, off, 64);
            float rs = 1.f / s0;
            #pragma unroll
            for (int t = 0; t < 4; ++t) p[t][reg] *= rs;
        }
        // P -> PS (bf16), rows are wave-private
        #pragma unroll
        for (int t = 0; t < 4; ++t)
            #pragma unroll
            for (int reg = 0; reg < 4; ++reg)
                SL[PS_OFF + (wv * 16 + l4 * 4 + reg) * 72 + t * 16 + l15] = f2bf(p[t][reg]);

        // ================= PV =================
        f32x4 av[2];
        av[0] = zf; av[1] = zf;
        #pragma unroll
        for (int kst = 0; kst < 2; ++kst) {
            short8 pa = *(const short8*)&SL[PS_OFF + (wv * 16 + l15) * 72 + kst * 32 + l4 * 8];
            #pragma unroll
            for (int dt = 0; dt < 2; ++dt) {
                short8 bv = *(const short8*)&SL[VT_OFF + (dt * 16 + l15) * 72 + kst * 32 + l4 * 8];
                av[dt] = __builtin_amdgcn_mfma_f32_16x16x32_bf16(pa, bv, av[dt], 0, 0, 0);
            }
        }
        #pragma unroll
        for (int dt = 0; dt < 2; ++dt)
            #pragma unroll
            for (int reg = 0; reg < 4; ++reg)
                SL[AV_OFF + (wv * 16 + l4 * 4 + reg) * 40 + dt * 16 + l15] = f2bf(av[dt][reg]);

        __syncthreads();   // proj frags staged + AV/PS coherent

        // ================= proj partial =================
        short8 aa = *(const short8*)&SL[AV_OFF + (wv * 16 + l15) * 40 + l4 * 8];
        #pragma unroll
        for (int nt = 0; nt < 24; ++nt) {
            short8 bp;
            if constexpr (WPREP) bp = *(const short8*)&SL[PROJ_ST + nt * 512 + lane * 8];
            else                 bp = gather_bf(proj_w, nt * 16 + l15, h * 32 + l4 * 8);
            pacc[nt] = __builtin_amdgcn_mfma_f32_16x16x32_bf16(aa, bp, pacc[nt], 0, 0, 0);
        }
    }

    // ================= epilogue: +proj_b, store =================
    {
        float* op = out + xbase;
        #pragma unroll
        for (int nt = 0; nt < 24; ++nt) {
            const float pb = proj_b[nt * 16 + l15];
            #pragma unroll
            for (int reg = 0; reg < 4; ++reg) {
                const int i = wv * 16 + l4 * 4 + reg;
                if (i < NTOK) op[i * DIMC + nt * 16 + l15] = pacc[nt][reg] + pb;
            }
        }
    }
}

extern "C" void kernel_launch(void* const* d_in, const int* in_sizes, int n_in,
                              void* d_out, int out_size, void* d_ws, size_t ws_size,
                              hipStream_t stream) {
    const float* x          = (const float*)d_in[0];
    const float* mask       = (const float*)d_in[1];
    const float* qkv_w      = (const float*)d_in[2];
    const float* qkv_b      = (const float*)d_in[3];
    const float* proj_w     = (const float*)d_in[4];
    const float* proj_b     = (const float*)d_in[5];
    const float* bias_table = (const float*)d_in[6];
    float* out = (float*)d_out;

    const size_t need = (size_t)(NQFRAG + NPFRAG) * 64 * 8 * sizeof(short);
    if (ws_size >= need) {
        short* wqb = (short*)d_ws;
        short* wpb = wqb + (size_t)NQFRAG * 512;
        prep_weights<<<288, 256, 0, stream>>>(qkv_w, proj_w, wqb, wpb);
        winattn_mfma<true><<<4096, 256, 0, stream>>>(x, mask, qkv_w, qkv_b, proj_w,
                                                     proj_b, bias_table, wqb, wpb, out);
    } else {
        winattn_mfma<false><<<4096, 256, 0, stream>>>(x, mask, qkv_w, qkv_b, proj_w,
                                                      proj_b, bias_table, nullptr, nullptr, out);
    }
}

// Round 4
// 957.868 us; speedup vs baseline: 51.9602x; 1.1609x over previous
//
#include <hip/hip_runtime.h>
#include <hip/hip_bf16.h>

#define NTOK 49
#define DIMC 384
#define NH 12
#define QSCALE 0.17677669529663687f

typedef __attribute__((ext_vector_type(8))) short short8;
typedef __attribute__((ext_vector_type(4))) float f32x4;
typedef unsigned int u32;

// LDS layout (short elements)
#define STG_OFF 0        // 2 bufs x 12 frags x 512 = 12288
#define KS_OFF  12288    // [64][40] = 2560
#define VT_OFF  14848    // [32][72] = 2304
#define PS_OFF  17152    // [64][72] = 4608
#define QA_OFF  21760    // [64][40] = 2560  (q, then AV reuse)
#define BT_OFF  24320    // 169*12 = 2028 -> pad 2032
#define QB_OFF  26352    // 1152
#define SL_TOT  27504    // 55008 bytes -> 2 blocks/CU by LDS

#define NQFRAG (NH * 6 * 12)   // 864 qkv fragments
#define NPFRAG (NH * 24)       // 288 proj fragments

__device__ __forceinline__ short f2bf(float f) {
    __bf16 h = (__bf16)f;
    return __builtin_bit_cast(short, h);
}
__device__ __forceinline__ float bf2f(short s) {
    u32 u = ((u32)(unsigned short)s) << 16;
    return __builtin_bit_cast(float, u);
}
__device__ __forceinline__ int cof(int p) { return 13 * (p / 7) + (p % 7); }

__device__ __forceinline__ void gld_lds16(const void* g, void* l) {
    __builtin_amdgcn_global_load_lds(
        (const __attribute__((address_space(1))) u32*)g,
        (__attribute__((address_space(3))) u32*)l, 16, 0, 0);
}

// fallback gather (fp32 source, uncoalesced — correctness path only)
__device__ __forceinline__ short8 gather_bf(const float* __restrict__ w, int row, int k0) {
    const float* p = w + row * DIMC + k0;
    float4 a = *(const float4*)p;
    float4 b = *(const float4*)(p + 4);
    short8 r;
    r[0]=f2bf(a.x); r[1]=f2bf(a.y); r[2]=f2bf(a.z); r[3]=f2bf(a.w);
    r[4]=f2bf(b.x); r[5]=f2bf(b.y); r[6]=f2bf(b.z); r[7]=f2bf(b.w);
    return r;
}

// -------- prep: fragment-tiled bf16 weights --------
__global__ void prep_weights(const float* __restrict__ qw, const float* __restrict__ pw,
                             short* __restrict__ wqb, short* __restrict__ wpb) {
    int gt = blockIdx.x * blockDim.x + threadIdx.x;
    if (gt < NQFRAG * 64) {
        int F = gt >> 6, lane = gt & 63;
        int h = F / 72, r = F % 72;
        int nt = r / 12, ks = r % 12;
        int l15 = lane & 15, l4 = lane >> 4;
        int grow = (nt >> 1) * DIMC + h * 32 + (nt & 1) * 16 + l15;
        const float* src = qw + grow * DIMC + ks * 32 + l4 * 8;
        short8 o;
        #pragma unroll
        for (int e = 0; e < 8; ++e) o[e] = f2bf(src[e]);
        *(short8*)(wqb + gt * 8) = o;
    } else if (gt < NQFRAG * 64 + NPFRAG * 64) {
        int t = gt - NQFRAG * 64;
        int G = t >> 6, lane = t & 63;
        int h = G / 24, nt = G % 24;
        int l15 = lane & 15, l4 = lane >> 4;
        const float* src = pw + (nt * 16 + l15) * DIMC + h * 32 + l4 * 8;
        short8 o;
        #pragma unroll
        for (int e = 0; e < 8; ++e) o[e] = f2bf(src[e]);
        *(short8*)(wpb + t * 8) = o;
    }
}

template<bool WPREP>
__global__ __launch_bounds__(256, 2)
void winattn_mfma(const float* __restrict__ x, const float* __restrict__ mask,
                  const float* __restrict__ qkv_w, const float* __restrict__ qkv_b,
                  const float* __restrict__ proj_w, const float* __restrict__ proj_b,
                  const float* __restrict__ bias_table,
                  const short* __restrict__ wqb, const short* __restrict__ wpb,
                  float* __restrict__ out)
{
    __shared__ short SL[SL_TOT] __attribute__((aligned(128)));

    const int tid  = threadIdx.x;
    const int wv   = tid >> 6;
    const int lane = tid & 63;
    const int l15  = lane & 15;
    const int l4   = lane >> 4;
    const int win  = blockIdx.x;
    const int xbase = win * (NTOK * DIMC);

    // ---- stage bias_table + qkv_b to LDS (bf16) — removes all in-loop compiler vmem ----
    for (int i = tid; i < 169 * NH; i += 256) SL[BT_OFF + i] = f2bf(bias_table[i]);
    for (int i = tid; i < 3 * DIMC; i += 256) SL[QB_OFF + i] = f2bf(qkv_b[i]);

    // ---- x A-fragments in registers: 12 k-steps x short8 ----
    short8 xf[12];
    {
        const int row = wv * 16 + l15;
        const bool valid = row < NTOK;
        const float* xr = x + xbase + row * DIMC;
        #pragma unroll
        for (int ks = 0; ks < 12; ++ks) {
            short8 r;
            if (valid) {
                float4 a = *(const float4*)(xr + ks * 32 + l4 * 8);
                float4 b = *(const float4*)(xr + ks * 32 + l4 * 8 + 4);
                r[0]=f2bf(a.x); r[1]=f2bf(a.y); r[2]=f2bf(a.z); r[3]=f2bf(a.w);
                r[4]=f2bf(b.x); r[5]=f2bf(b.y); r[6]=f2bf(b.z); r[7]=f2bf(b.w);
            } else {
                r = (short8)0;
            }
            xf[ks] = r;
        }
    }

    // ---- mask + rel-idx precompute ----
    float mv[4][4];
    int   bidx[4][4];      // (cofi+cofm)*NH, byte-ready LDS index
    float negm[4];
    {
        const float* maskp = mask + (win & 63) * (NTOK * NTOK);
        int cofi[4], cofm[4];
        #pragma unroll
        for (int t = 0; t < 4; ++t) {
            int m = t * 16 + l15;
            negm[t] = (m < NTOK) ? 0.f : -1e30f;
            int mm = m < NTOK ? m : 48;
            cofm[t] = cof(48 - mm);
            #pragma unroll
            for (int reg = 0; reg < 4; ++reg) {
                int i = wv * 16 + l4 * 4 + reg;
                mv[t][reg] = (i < NTOK && m < NTOK) ? maskp[i * NTOK + m] : 0.f;
            }
        }
        #pragma unroll
        for (int reg = 0; reg < 4; ++reg) {
            int i = wv * 16 + l4 * 4 + reg;
            cofi[reg] = cof(i < NTOK ? i : 48);
        }
        #pragma unroll
        for (int t = 0; t < 4; ++t)
            #pragma unroll
            for (int reg = 0; reg < 4; ++reg)
                bidx[t][reg] = (cofi[reg] + cofm[t]) * NH;
    }

    f32x4 pacc[24];
    #pragma unroll
    for (int t = 0; t < 24; ++t) pacc[t] = (f32x4){0.f, 0.f, 0.f, 0.f};
    const f32x4 zf = (f32x4){0.f, 0.f, 0.f, 0.f};

    __syncthreads();   // BT/QB visible

    // issue head-0 chunk-0
    if constexpr (WPREP) {
        #pragma unroll
        for (int t = 0; t < 3; ++t) {
            int j = wv * 3 + t;
            int F = (j >> 1) * 12 + (j & 1);
            gld_lds16(wqb + F * 512 + lane * 8, &SL[STG_OFF + j * 512]);
        }
    }

    #pragma unroll 1
    for (int h = 0; h < NH; ++h) {
        // ================= phase A: qkv GEMM, pipelined chunks =================
        f32x4 qa[6];
        #pragma unroll
        for (int nt = 0; nt < 6; ++nt) qa[nt] = zf;

        #pragma unroll
        for (int c = 0; c < 6; ++c) {
            __builtin_amdgcn_sched_barrier(0);
            asm volatile("s_waitcnt vmcnt(0)" ::: "memory");
            __builtin_amdgcn_s_barrier();
            __builtin_amdgcn_sched_barrier(0);
            if constexpr (WPREP) {
                if (c < 5) {
                    #pragma unroll
                    for (int t = 0; t < 3; ++t) {
                        int j = wv * 3 + t;
                        int F = (h * 6 + (j >> 1)) * 12 + 2 * (c + 1) + (j & 1);
                        gld_lds16(wqb + F * 512 + lane * 8,
                                  &SL[STG_OFF + ((c + 1) & 1) * 6144 + j * 512]);
                    }
                }
            }
            #pragma unroll
            for (int j = 0; j < 12; ++j) {
                short8 b;
                if constexpr (WPREP) {
                    b = *(const short8*)&SL[STG_OFF + (c & 1) * 6144 + j * 512 + lane * 8];
                } else {
                    const int grow = ((j >> 1) >> 1) * DIMC + h * 32 + ((j >> 1) & 1) * 16 + l15;
                    b = gather_bf(qkv_w, grow, (2 * c + (j & 1)) * 32 + l4 * 8);
                }
                qa[j >> 1] = __builtin_amdgcn_mfma_f32_16x16x32_bf16(
                    xf[2 * c + (j & 1)], b, qa[j >> 1], 0, 0, 0);
            }
        }

        // epilogue: +bias (from LDS), scale q; q->QA, k->KS, v->VT (bf16)
        #pragma unroll
        for (int nt = 0; nt < 6; ++nt) {
            const int sub = nt >> 1;
            const int colw = (nt & 1) * 16 + l15;
            const float bias = bf2f(SL[QB_OFF + sub * DIMC + h * 32 + colw]);
            #pragma unroll
            for (int reg = 0; reg < 4; ++reg) {
                const int tokg = wv * 16 + l4 * 4 + reg;
                float val = qa[nt][reg] + bias;
                if (sub == 0)      SL[QA_OFF + tokg * 40 + colw] = f2bf(val * QSCALE);
                else if (sub == 1) SL[KS_OFF + tokg * 40 + colw] = f2bf(val);
                else               SL[VT_OFF + colw * 72 + tokg] = f2bf(val);
            }
        }
        __syncthreads();

        // issue next head's chunk-0 (hides under attention + proj)
        if constexpr (WPREP) {
            if (h + 1 < NH) {
                #pragma unroll
                for (int t = 0; t < 3; ++t) {
                    int j = wv * 3 + t;
                    int F = ((h + 1) * 6 + (j >> 1)) * 12 + (j & 1);
                    gld_lds16(wqb + F * 512 + lane * 8, &SL[STG_OFF + j * 512]);
                }
            }
        }

        // ================= QK^T =================
        short8 aq = *(const short8*)&SL[QA_OFF + (wv * 16 + l15) * 40 + l4 * 8];
        f32x4 sc[4];
        #pragma unroll
        for (int t = 0; t < 4; ++t) {
            short8 bk = *(const short8*)&SL[KS_OFF + (t * 16 + l15) * 40 + l4 * 8];
            sc[t] = __builtin_amdgcn_mfma_f32_16x16x32_bf16(aq, bk, zf, 0, 0, 0);
        }
        // logits + rel-bias (LDS) + mask, softmax
        float p[4][4];
        #pragma unroll
        for (int t = 0; t < 4; ++t) {
            #pragma unroll
            for (int reg = 0; reg < 4; ++reg) {
                float bt = bf2f(SL[BT_OFF + bidx[t][reg] + h]);
                p[t][reg] = sc[t][reg] + mv[t][reg] + bt + negm[t];
            }
        }
        #pragma unroll
        for (int reg = 0; reg < 4; ++reg) {
            float mx = fmaxf(fmaxf(p[0][reg], p[1][reg]), fmaxf(p[2][reg], p[3][reg]));
            #pragma unroll
            for (int off = 8; off >= 1; off >>= 1) mx = fmaxf(mx, __shfl_xor(mx, off, 64));
            float s0 = 0.f;
            #pragma unroll
            for (int t = 0; t < 4; ++t) { p[t][reg] = __expf(p[t][reg] - mx); s0 += p[t][reg]; }
            #pragma unroll
            for (int off = 8; off >= 1; off >>= 1) s0 += __shfl_xor(s0, off, 64);
            float rs = 1.f / s0;
            #pragma unroll
            for (int t = 0; t < 4; ++t) p[t][reg] *= rs;
        }
        // P -> PS (bf16), rows wave-private
        #pragma unroll
        for (int t = 0; t < 4; ++t)
            #pragma unroll
            for (int reg = 0; reg < 4; ++reg)
                SL[PS_OFF + (wv * 16 + l4 * 4 + reg) * 72 + t * 16 + l15] = f2bf(p[t][reg]);

        // ================= PV =================
        f32x4 av[2];
        av[0] = zf; av[1] = zf;
        #pragma unroll
        for (int kst = 0; kst < 2; ++kst) {
            short8 pa = *(const short8*)&SL[PS_OFF + (wv * 16 + l15) * 72 + kst * 32 + l4 * 8];
            #pragma unroll
            for (int dt = 0; dt < 2; ++dt) {
                short8 bv = *(const short8*)&SL[VT_OFF + (dt * 16 + l15) * 72 + kst * 32 + l4 * 8];
                av[dt] = __builtin_amdgcn_mfma_f32_16x16x32_bf16(pa, bv, av[dt], 0, 0, 0);
            }
        }
        // AV -> QA buffer (wave-private rows; q no longer needed)
        #pragma unroll
        for (int dt = 0; dt < 2; ++dt)
            #pragma unroll
            for (int reg = 0; reg < 4; ++reg)
                SL[QA_OFF + (wv * 16 + l4 * 4 + reg) * 40 + dt * 16 + l15] = f2bf(av[dt][reg]);

        // ================= proj partial (B direct from global frag-tiled) =================
        short8 aa = *(const short8*)&SL[QA_OFF + (wv * 16 + l15) * 40 + l4 * 8];
        #pragma unroll
        for (int nt = 0; nt < 24; ++nt) {
            short8 bp;
            if constexpr (WPREP) bp = *(const short8*)(wpb + (h * 24 + nt) * 512 + lane * 8);
            else                 bp = gather_bf(proj_w, nt * 16 + l15, h * 32 + l4 * 8);
            pacc[nt] = __builtin_amdgcn_mfma_f32_16x16x32_bf16(aa, bp, pacc[nt], 0, 0, 0);
        }
        // no barrier: next head's chunk barriers order KS/VT reuse
    }

    // ================= epilogue: +proj_b, store =================
    {
        float* op = out + xbase;
        #pragma unroll
        for (int nt = 0; nt < 24; ++nt) {
            const float pb = proj_b[nt * 16 + l15];
            #pragma unroll
            for (int reg = 0; reg < 4; ++reg) {
                const int i = wv * 16 + l4 * 4 + reg;
                if (i < NTOK) op[i * DIMC + nt * 16 + l15] = pacc[nt][reg] + pb;
            }
        }
    }
}

extern "C" void kernel_launch(void* const* d_in, const int* in_sizes, int n_in,
                              void* d_out, int out_size, void* d_ws, size_t ws_size,
                              hipStream_t stream) {
    const float* x          = (const float*)d_in[0];
    const float* mask       = (const float*)d_in[1];
    const float* qkv_w      = (const float*)d_in[2];
    const float* qkv_b      = (const float*)d_in[3];
    const float* proj_w     = (const float*)d_in[4];
    const float* proj_b     = (const float*)d_in[5];
    const float* bias_table = (const float*)d_in[6];
    float* out = (float*)d_out;

    const size_t need = (size_t)(NQFRAG + NPFRAG) * 64 * 8 * sizeof(short);
    if (ws_size >= need) {
        short* wqb = (short*)d_ws;
        short* wpb = wqb + (size_t)NQFRAG * 512;
        prep_weights<<<288, 256, 0, stream>>>(qkv_w, proj_w, wqb, wpb);
        winattn_mfma<true><<<4096, 256, 0, stream>>>(x, mask, qkv_w, qkv_b, proj_w,
                                                     proj_b, bias_table, wqb, wpb, out);
    } else {
        winattn_mfma<false><<<4096, 256, 0, stream>>>(x, mask, qkv_w, qkv_b, proj_w,
                                                      proj_b, bias_table, nullptr, nullptr, out);
    }
}

// Round 6
// 737.809 us; speedup vs baseline: 67.4579x; 1.2983x over previous
//
#include <hip/hip_runtime.h>
#include <hip/hip_bf16.h>

#define NTOK 49
#define DIMC 384
#define NH 12
#define QSCALE 0.17677669529663687f

typedef __attribute__((ext_vector_type(8))) short short8;
typedef __attribute__((ext_vector_type(4))) float f32x4;
typedef unsigned int u32;

// ---------------- LDS layout for fused kernel (short units) ----------------
#define STG_OFF 0
#define KS_OFF  12288
#define VT_OFF  14336
#define PS_OFF  16384
#define QA_OFF  20480
#define BT_OFF  22528
#define QB_OFF  24556
#define SL_TOT  25708     // 51416 B -> 3 blocks/CU

#define NQFRAG (NH * 6 * 12)               // 864 qkv fragments
#define WQB_SHORTS (NQFRAG * 512)          // 884736 B
#define WPB_SHORTS (3 * 6 * 8192)          // 294912 B (3 nb x 6 kc x 16KB tiles)
#define MB_TILES 1568                      // 4096*49/128 — exact
#define AV_BYTES ((size_t)MB_TILES * 6 * 16384)   // 154140672 B

__device__ __forceinline__ short f2bf(float f) {
    __bf16 h = (__bf16)f;
    return __builtin_bit_cast(short, h);
}
__device__ __forceinline__ float bf2f(short s) {
    u32 u = ((u32)(unsigned short)s) << 16;
    return __builtin_bit_cast(float, u);
}
__device__ __forceinline__ int cof(int p) { return 13 * (p / 7) + (p % 7); }

__device__ __forceinline__ void gld_lds16(const void* g, void* l) {
    __builtin_amdgcn_global_load_lds(
        (const __attribute__((address_space(1))) u32*)g,
        (__attribute__((address_space(3))) u32*)l, 16, 0, 0);
}

// fallback gather (fp32 source, uncoalesced — correctness path only)
__device__ __forceinline__ short8 gather_bf(const float* __restrict__ w, int row, int k0) {
    const float* p = w + row * DIMC + k0;
    float4 a = *(const float4*)p;
    float4 b = *(const float4*)(p + 4);
    short8 r;
    r[0]=f2bf(a.x); r[1]=f2bf(a.y); r[2]=f2bf(a.z); r[3]=f2bf(a.w);
    r[4]=f2bf(b.x); r[5]=f2bf(b.y); r[6]=f2bf(b.z); r[7]=f2bf(b.w);
    return r;
}

// -------- prep: fragment-tiled bf16 qkv weights + blocked-swizzled proj weights --------
__global__ void prep_weights(const float* __restrict__ qw, const float* __restrict__ pw,
                             short* __restrict__ wqb, short* __restrict__ wpb) {
    int gt = blockIdx.x * blockDim.x + threadIdx.x;
    if (gt < NQFRAG * 64) {
        int F = gt >> 6, lane = gt & 63;
        int h = F / 72, r = F % 72;
        int nt = r / 12, ks = r % 12;
        int l15 = lane & 15, l4 = lane >> 4;
        int grow = (nt >> 1) * DIMC + h * 32 + (nt & 1) * 16 + l15;
        const float* src = qw + grow * DIMC + ks * 32 + l4 * 8;
        short8 o;
        #pragma unroll
        for (int e = 0; e < 8; ++e) o[e] = f2bf(src[e]);
        *(short8*)(wqb + gt * 8) = o;
    } else if (gt < NQFRAG * 64 + 3 * 6 * 128 * 8) {
        int t2 = gt - NQFRAG * 64;        // [0, 18432)
        int g  = t2 & 7;                  // 16B group in row
        int r  = (t2 >> 3) & 127;         // row (= n within tile)
        int kc = (t2 >> 10) % 6;
        int nb = t2 / 6144;
        int k0 = kc * 64 + ((g ^ (r & 7)) << 3);
        const float* src = pw + (nb * 128 + r) * DIMC + k0;
        short8 o;
        #pragma unroll
        for (int e = 0; e < 8; ++e) o[e] = f2bf(src[e]);
        *(short8*)(wpb + (nb * 6 + kc) * 8192 + r * 64 + g * 8) = o;
    }
}

// ================= fused qkv + attention (no proj), AV -> ws =================
__global__ __launch_bounds__(256, 3)
void winattn_fused(const float* __restrict__ x, const float* __restrict__ mask,
                   const float* __restrict__ qkv_b, const float* __restrict__ bias_table,
                   const short* __restrict__ wqb, char* __restrict__ avb)
{
    __shared__ short SL[SL_TOT] __attribute__((aligned(128)));

    const int tid  = threadIdx.x;
    const int wv   = tid >> 6;
    const int lane = tid & 63;
    const int l15  = lane & 15;
    const int l4   = lane >> 4;
    const int win  = blockIdx.x;
    const int xbase = win * (NTOK * DIMC);

    // ---- stage bias_table + qkv_b to LDS (bf16) ----
    for (int i = tid; i < 169 * NH; i += 256) SL[BT_OFF + i] = f2bf(bias_table[i]);
    for (int i = tid; i < 3 * DIMC; i += 256) SL[QB_OFF + i] = f2bf(qkv_b[i]);

    // ---- x A-fragments in registers: 12 k-steps x short8 ----
    short8 xf[12];
    {
        const int row = wv * 16 + l15;
        const bool valid = row < NTOK;
        const float* xr = x + xbase + row * DIMC;
        #pragma unroll
        for (int ks = 0; ks < 12; ++ks) {
            short8 r;
            if (valid) {
                float4 a = *(const float4*)(xr + ks * 32 + l4 * 8);
                float4 b = *(const float4*)(xr + ks * 32 + l4 * 8 + 4);
                r[0]=f2bf(a.x); r[1]=f2bf(a.y); r[2]=f2bf(a.z); r[3]=f2bf(a.w);
                r[4]=f2bf(b.x); r[5]=f2bf(b.y); r[6]=f2bf(b.z); r[7]=f2bf(b.w);
            } else {
                r = (short8)0;
            }
            xf[ks] = r;
        }
    }

    // ---- mask + rel-idx precompute ----
    float mv[4][4];
    int   bidx[4][4];
    float negm[4];
    {
        const float* maskp = mask + (win & 63) * (NTOK * NTOK);
        int cofi[4], cofm[4];
        #pragma unroll
        for (int t = 0; t < 4; ++t) {
            int m = t * 16 + l15;
            negm[t] = (m < NTOK) ? 0.f : -1e30f;
            int mm = m < NTOK ? m : 48;
            cofm[t] = cof(48 - mm);
            #pragma unroll
            for (int reg = 0; reg < 4; ++reg) {
                int i = wv * 16 + l4 * 4 + reg;
                mv[t][reg] = (i < NTOK && m < NTOK) ? maskp[i * NTOK + m] : 0.f;
            }
        }
        #pragma unroll
        for (int reg = 0; reg < 4; ++reg) {
            int i = wv * 16 + l4 * 4 + reg;
            cofi[reg] = cof(i < NTOK ? i : 48);
        }
        #pragma unroll
        for (int t = 0; t < 4; ++t)
            #pragma unroll
            for (int reg = 0; reg < 4; ++reg)
                bidx[t][reg] = (cofi[reg] + cofm[t]) * NH;
    }

    const f32x4 zf = (f32x4){0.f, 0.f, 0.f, 0.f};

    __syncthreads();   // BT/QB visible

    // prologue: issue head-0 chunk-0 (buf 0)
    #pragma unroll
    for (int t = 0; t < 3; ++t) {
        int j = wv * 3 + t;
        int F = (j >> 1) * 12 + (j & 1);
        gld_lds16(wqb + F * 512 + lane * 8, &SL[STG_OFF + j * 512]);
    }

    #pragma unroll 1
    for (int h = 0; h < NH; ++h) {
        // ================= phase A: qkv GEMM, pipelined chunks =================
        f32x4 qa[6];
        #pragma unroll
        for (int nt = 0; nt < 6; ++nt) qa[nt] = zf;

        #pragma unroll
        for (int c = 0; c < 6; ++c) {
            __builtin_amdgcn_sched_barrier(0);
            asm volatile("s_waitcnt vmcnt(0)" ::: "memory");
            __builtin_amdgcn_s_barrier();
            __builtin_amdgcn_sched_barrier(0);
            // issue next chunk (buf alternates c&1 since 6 is even)
            {
                int hh = (c < 5) ? h : h + 1;
                int cc = (c < 5) ? c + 1 : 0;
                if (hh < NH) {
                    #pragma unroll
                    for (int t = 0; t < 3; ++t) {
                        int j = wv * 3 + t;
                        int F = (hh * 6 + (j >> 1)) * 12 + 2 * cc + (j & 1);
                        gld_lds16(wqb + F * 512 + lane * 8,
                                  &SL[STG_OFF + ((c + 1) & 1) * 6144 + j * 512]);
                    }
                }
            }
            __builtin_amdgcn_s_setprio(1);
            #pragma unroll
            for (int j = 0; j < 12; ++j) {
                short8 b = *(const short8*)&SL[STG_OFF + (c & 1) * 6144 + j * 512 + lane * 8];
                qa[j >> 1] = __builtin_amdgcn_mfma_f32_16x16x32_bf16(
                    xf[2 * c + (j & 1)], b, qa[j >> 1], 0, 0, 0);
            }
            __builtin_amdgcn_s_setprio(0);
        }

        // epilogue: +bias (LDS), scale q; q->QA, k->KS (swz 64B rows), v->VT (swz 128B rows)
        #pragma unroll
        for (int nt = 0; nt < 6; ++nt) {
            const int sub = nt >> 1;
            const int colw = (nt & 1) * 16 + l15;
            const float bias = bf2f(SL[QB_OFF + sub * DIMC + h * 32 + colw]);
            #pragma unroll
            for (int reg = 0; reg < 4; ++reg) {
                const int tokg = wv * 16 + l4 * 4 + reg;
                float val = qa[nt][reg] + bias;
                if (sub == 0) {
                    int byt = tokg * 64 + (((colw << 1)) ^ ((tokg & 3) << 4));
                    SL[QA_OFF + (byt >> 1)] = f2bf(val * QSCALE);
                } else if (sub == 1) {
                    int byt = tokg * 64 + (((colw << 1)) ^ ((tokg & 3) << 4));
                    SL[KS_OFF + (byt >> 1)] = f2bf(val);
                } else {
                    int byt = colw * 128 + (((tokg << 1)) ^ ((colw & 7) << 4));
                    SL[VT_OFF + (byt >> 1)] = f2bf(val);
                }
            }
        }
        __syncthreads();

        // ================= QK^T =================
        short8 aq;
        {
            int row = wv * 16 + l15;
            int byt = row * 64 + ((l4 * 16) ^ ((row & 3) << 4));
            aq = *(const short8*)&SL[QA_OFF + (byt >> 1)];
        }
        f32x4 sc[4];
        #pragma unroll
        for (int t = 0; t < 4; ++t) {
            int row = t * 16 + l15;
            int byt = row * 64 + ((l4 * 16) ^ ((row & 3) << 4));
            short8 bk = *(const short8*)&SL[KS_OFF + (byt >> 1)];
            sc[t] = __builtin_amdgcn_mfma_f32_16x16x32_bf16(aq, bk, zf, 0, 0, 0);
        }
        // logits + rel-bias + mask, softmax
        float p[4][4];
        #pragma unroll
        for (int t = 0; t < 4; ++t) {
            #pragma unroll
            for (int reg = 0; reg < 4; ++reg) {
                float bt = bf2f(SL[BT_OFF + bidx[t][reg] + h]);
                p[t][reg] = sc[t][reg] + mv[t][reg] + bt + negm[t];
            }
        }
        #pragma unroll
        for (int reg = 0; reg < 4; ++reg) {
            float mx = fmaxf(fmaxf(p[0][reg], p[1][reg]), fmaxf(p[2][reg], p[3][reg]));
            #pragma unroll
            for (int off = 8; off >= 1; off >>= 1) mx = fmaxf(mx, __shfl_xor(mx, off, 64));
            float s0 = 0.f;
            #pragma unroll
            for (int t = 0; t < 4; ++t) { p[t][reg] = __expf(p[t][reg] - mx); s0 += p[t][reg]; }
            #pragma unroll
            for (int off = 8; off >= 1; off >>= 1) s0 += __shfl_xor(s0, off, 64);
            float rs = 1.f / s0;
            #pragma unroll
            for (int t = 0; t < 4; ++t) p[t][reg] *= rs;
        }
        // P -> PS (bf16, swizzled 128B rows; rows wave-private)
        #pragma unroll
        for (int t = 0; t < 4; ++t)
            #pragma unroll
            for (int reg = 0; reg < 4; ++reg) {
                int row = wv * 16 + l4 * 4 + reg;
                int byt = row * 128 + ((((t * 16 + l15) << 1)) ^ ((row & 7) << 4));
                SL[PS_OFF + (byt >> 1)] = f2bf(p[t][reg]);
            }

        // ================= PV =================
        f32x4 av[2];
        av[0] = zf; av[1] = zf;
        #pragma unroll
        for (int kst = 0; kst < 2; ++kst) {
            short8 pa;
            {
                int row = wv * 16 + l15;
                int byt = row * 128 + ((kst * 64 + l4 * 16) ^ ((row & 7) << 4));
                pa = *(const short8*)&SL[PS_OFF + (byt >> 1)];
            }
            #pragma unroll
            for (int dt = 0; dt < 2; ++dt) {
                int d = dt * 16 + l15;
                int byt = d * 128 + ((kst * 64 + l4 * 16) ^ ((d & 7) << 4));
                short8 bv = *(const short8*)&SL[VT_OFF + (byt >> 1)];
                av[dt] = __builtin_amdgcn_mfma_f32_16x16x32_bf16(pa, bv, av[dt], 0, 0, 0);
            }
        }
        // AV -> ws, blocked-swizzled proj-GEMM tile layout
        #pragma unroll
        for (int dt = 0; dt < 2; ++dt)
            #pragma unroll
            for (int reg = 0; reg < 4; ++reg) {
                int tok = wv * 16 + l4 * 4 + reg;
                if (tok < NTOK) {
                    int gt = win * NTOK + tok;
                    int mb = gt >> 7, r = gt & 127;
                    int inner = ((((h & 1) << 6) | ((dt * 16 + l15) << 1))) ^ ((r & 7) << 4);
                    *(short*)(avb + (size_t)(mb * 6 + (h >> 1)) * 16384 + r * 128 + inner)
                        = f2bf(av[dt][reg]);
                }
            }
        // next head's chunk barriers order KS/VT/QA reuse
    }
}

// ================= proj GEMM: out[200704,384] = AV @ projW^T + b =================
__global__ __launch_bounds__(256, 2)
void proj_gemm(const char* __restrict__ avb, const short* __restrict__ wpb,
               const float* __restrict__ proj_b, float* __restrict__ out)
{
    __shared__ char LC[2][32768] __attribute__((aligned(128)));

    const int tid = threadIdx.x;
    const int wv = tid >> 6, lane = tid & 63;
    const int l15 = lane & 15, l4 = lane >> 4;
    const int wr = wv >> 1, wc = wv & 1;
    const int mb = blockIdx.x / 3, nb = blockIdx.x % 3;

    const char* asrc = avb + (size_t)mb * 6 * 16384;
    const char* bsrc = (const char*)wpb + (size_t)nb * 6 * 16384;

    f32x4 acc[4][4];
    #pragma unroll
    for (int mi = 0; mi < 4; ++mi)
        #pragma unroll
        for (int ni = 0; ni < 4; ++ni) acc[mi][ni] = (f32x4){0.f, 0.f, 0.f, 0.f};

    // prologue stage kc=0 into buf 0
    #pragma unroll
    for (int it = 0; it < 4; ++it) {
        int L = (wv * 4 + it) * 1024;
        gld_lds16(asrc + L + lane * 16, &LC[0][L]);
        gld_lds16(bsrc + L + lane * 16, &LC[0][16384 + L]);
    }

    #pragma unroll
    for (int kc = 0; kc < 6; ++kc) {
        __builtin_amdgcn_sched_barrier(0);
        asm volatile("s_waitcnt vmcnt(0)" ::: "memory");
        __builtin_amdgcn_s_barrier();
        __builtin_amdgcn_sched_barrier(0);
        if (kc < 5) {
            #pragma unroll
            for (int it = 0; it < 4; ++it) {
                int L = (wv * 4 + it) * 1024;
                gld_lds16(asrc + (kc + 1) * 16384 + L + lane * 16, &LC[(kc + 1) & 1][L]);
                gld_lds16(bsrc + (kc + 1) * 16384 + L + lane * 16, &LC[(kc + 1) & 1][16384 + L]);
            }
        }
        const char* bufp = LC[kc & 1];
        __builtin_amdgcn_s_setprio(1);
        #pragma unroll
        for (int ksub = 0; ksub < 2; ++ksub) {
            short8 a[4], b[4];
            #pragma unroll
            for (int mi = 0; mi < 4; ++mi) {
                int row = wr * 64 + mi * 16 + l15;
                a[mi] = *(const short8*)(bufp + row * 128 +
                        ((ksub * 64 + l4 * 16) ^ ((row & 7) << 4)));
            }
            #pragma unroll
            for (int ni = 0; ni < 4; ++ni) {
                int row = wc * 64 + ni * 16 + l15;
                b[ni] = *(const short8*)(bufp + 16384 + row * 128 +
                        ((ksub * 64 + l4 * 16) ^ ((row & 7) << 4)));
            }
            #pragma unroll
            for (int mi = 0; mi < 4; ++mi)
                #pragma unroll
                for (int ni = 0; ni < 4; ++ni)
                    acc[mi][ni] = __builtin_amdgcn_mfma_f32_16x16x32_bf16(
                        a[mi], b[ni], acc[mi][ni], 0, 0, 0);
        }
        __builtin_amdgcn_s_setprio(0);
    }

    // epilogue
    float pb[4];
    #pragma unroll
    for (int ni = 0; ni < 4; ++ni) pb[ni] = proj_b[nb * 128 + wc * 64 + ni * 16 + l15];
    #pragma unroll
    for (int mi = 0; mi < 4; ++mi) {
        #pragma unroll
        for (int ni = 0; ni < 4; ++ni) {
            #pragma unroll
            for (int reg = 0; reg < 4; ++reg) {
                size_t row = (size_t)(mb * 128 + wr * 64 + mi * 16 + l4 * 4 + reg);
                out[row * DIMC + nb * 128 + wc * 64 + ni * 16 + l15] = acc[mi][ni][reg] + pb[ni];
            }
        }
    }
}

// ================= fallback: monolithic gather kernel (no ws) =================
__global__ __launch_bounds__(256, 2)
void winattn_fallback(const float* __restrict__ x, const float* __restrict__ mask,
                      const float* __restrict__ qkv_w, const float* __restrict__ qkv_b,
                      const float* __restrict__ proj_w, const float* __restrict__ proj_b,
                      const float* __restrict__ bias_table, float* __restrict__ out)
{
    __shared__ short SL[SL_TOT] __attribute__((aligned(128)));
    const int tid = threadIdx.x, wv = tid >> 6, lane = tid & 63;
    const int l15 = lane & 15, l4 = lane >> 4;
    const int win = blockIdx.x;
    const int xbase = win * (NTOK * DIMC);

    short8 xf[12];
    {
        const int row = wv * 16 + l15;
        const bool valid = row < NTOK;
        const float* xr = x + xbase + row * DIMC;
        #pragma unroll
        for (int ks = 0; ks < 12; ++ks)
            xf[ks] = valid ? gather_bf(xr, 0, ks * 32 + l4 * 8) : (short8)0;
    }
    float mv[4][4]; int bidx[4][4]; float negm[4];
    {
        const float* maskp = mask + (win & 63) * (NTOK * NTOK);
        int cofi[4], cofm[4];
        #pragma unroll
        for (int t = 0; t < 4; ++t) {
            int m = t * 16 + l15;
            negm[t] = (m < NTOK) ? 0.f : -1e30f;
            cofm[t] = cof(48 - (m < NTOK ? m : 48));
            #pragma unroll
            for (int reg = 0; reg < 4; ++reg) {
                int i = wv * 16 + l4 * 4 + reg;
                mv[t][reg] = (i < NTOK && m < NTOK) ? maskp[i * NTOK + m] : 0.f;
            }
        }
        #pragma unroll
        for (int reg = 0; reg < 4; ++reg) {
            int i = wv * 16 + l4 * 4 + reg;
            cofi[reg] = cof(i < NTOK ? i : 48);
        }
        #pragma unroll
        for (int t = 0; t < 4; ++t)
            #pragma unroll
            for (int reg = 0; reg < 4; ++reg) bidx[t][reg] = (cofi[reg] + cofm[t]) * NH;
    }
    f32x4 pacc[24];
    #pragma unroll
    for (int t = 0; t < 24; ++t) pacc[t] = (f32x4){0.f, 0.f, 0.f, 0.f};
    const f32x4 zf = (f32x4){0.f, 0.f, 0.f, 0.f};
    __syncthreads();

    #pragma unroll 1
    for (int h = 0; h < NH; ++h) {
        f32x4 qa[6];
        #pragma unroll
        for (int nt = 0; nt < 6; ++nt) qa[nt] = zf;
        #pragma unroll
        for (int nt = 0; nt < 6; ++nt) {
            const int grow = (nt >> 1) * DIMC + h * 32 + (nt & 1) * 16 + l15;
            #pragma unroll
            for (int ks = 0; ks < 12; ++ks) {
                short8 b = gather_bf(qkv_w, grow, ks * 32 + l4 * 8);
                qa[nt] = __builtin_amdgcn_mfma_f32_16x16x32_bf16(xf[ks], b, qa[nt], 0, 0, 0);
            }
        }
        #pragma unroll
        for (int nt = 0; nt < 6; ++nt) {
            const int sub = nt >> 1;
            const int colw = (nt & 1) * 16 + l15;
            const float bias = qkv_b[sub * DIMC + h * 32 + colw];
            #pragma unroll
            for (int reg = 0; reg < 4; ++reg) {
                const int tokg = wv * 16 + l4 * 4 + reg;
                float val = qa[nt][reg] + bias;
                if (sub == 0) {
                    int byt = tokg * 64 + ((colw << 1) ^ ((tokg & 3) << 4));
                    SL[QA_OFF + (byt >> 1)] = f2bf(val * QSCALE);
                } else if (sub == 1) {
                    int byt = tokg * 64 + ((colw << 1) ^ ((tokg & 3) << 4));
                    SL[KS_OFF + (byt >> 1)] = f2bf(val);
                } else {
                    int byt = colw * 128 + ((tokg << 1) ^ ((colw & 7) << 4));
                    SL[VT_OFF + (byt >> 1)] = f2bf(val);
                }
            }
        }
        __syncthreads();
        short8 aq;
        { int row = wv*16+l15; int byt = row*64 + ((l4*16) ^ ((row&3)<<4));
          aq = *(const short8*)&SL[QA_OFF + (byt>>1)]; }
        f32x4 sc[4];
        #pragma unroll
        for (int t = 0; t < 4; ++t) {
            int row = t*16+l15; int byt = row*64 + ((l4*16) ^ ((row&3)<<4));
            short8 bk = *(const short8*)&SL[KS_OFF + (byt>>1)];
            sc[t] = __builtin_amdgcn_mfma_f32_16x16x32_bf16(aq, bk, zf, 0, 0, 0);
        }
        float p[4][4];
        #pragma unroll
        for (int t = 0; t < 4; ++t)
            #pragma unroll
            for (int reg = 0; reg < 4; ++reg)
                p[t][reg] = sc[t][reg] + mv[t][reg] + bias_table[bidx[t][reg] + h] + negm[t];
        #pragma unroll
        for (int reg = 0; reg < 4; ++reg) {
            float mx = fmaxf(fmaxf(p[0][reg], p[1][reg]), fmaxf(p[2][reg], p[3][reg]));
            #pragma unroll
            for (int off = 8; off >= 1; off >>= 1) mx = fmaxf(mx, __shfl_xor(mx, off, 64));
            float s0 = 0.f;
            #pragma unroll
            for (int t = 0; t < 4; ++t) { p[t][reg] = __expf(p[t][reg] - mx); s0 += p[t][reg]; }
            #pragma unroll
            for (int off = 8; off >= 1; off >>= 1) s0 += __shfl_xor(s0, off, 64);
            float rs = 1.f / s0;
            #pragma unroll
            for (int t = 0; t < 4; ++t) p[t][reg] *= rs;
        }
        #pragma unroll
        for (int t = 0; t < 4; ++t)
            #pragma unroll
            for (int reg = 0; reg < 4; ++reg) {
                int row = wv*16 + l4*4 + reg;
                int byt = row*128 + (((t*16+l15) << 1) ^ ((row&7)<<4));
                SL[PS_OFF + (byt>>1)] = f2bf(p[t][reg]);
            }
        f32x4 av[2]; av[0] = zf; av[1] = zf;
        #pragma unroll
        for (int kst = 0; kst < 2; ++kst) {
            short8 pa;
            { int row = wv*16+l15; int byt = row*128 + ((kst*64+l4*16) ^ ((row&7)<<4));
              pa = *(const short8*)&SL[PS_OFF + (byt>>1)]; }
            #pragma unroll
            for (int dt = 0; dt < 2; ++dt) {
                int d = dt*16+l15; int byt = d*128 + ((kst*64+l4*16) ^ ((d&7)<<4));
                short8 bv = *(const short8*)&SL[VT_OFF + (byt>>1)];
                av[dt] = __builtin_amdgcn_mfma_f32_16x16x32_bf16(pa, bv, av[dt], 0, 0, 0);
            }
        }
        __syncthreads();
        #pragma unroll
        for (int dt = 0; dt < 2; ++dt)
            #pragma unroll
            for (int reg = 0; reg < 4; ++reg) {
                int row = wv*16 + l4*4 + reg;
                int byt = row*64 + (((dt*16+l15) << 1) ^ ((row&3)<<4));
                SL[QA_OFF + (byt>>1)] = f2bf(av[dt][reg]);
            }
        __syncthreads();
        short8 aa;
        { int row = wv*16+l15; int byt = row*64 + ((l4*16) ^ ((row&3)<<4));
          aa = *(const short8*)&SL[QA_OFF + (byt>>1)]; }
        #pragma unroll
        for (int nt = 0; nt < 24; ++nt) {
            short8 bp = gather_bf(proj_w, nt * 16 + l15, h * 32 + l4 * 8);
            pacc[nt] = __builtin_amdgcn_mfma_f32_16x16x32_bf16(aa, bp, pacc[nt], 0, 0, 0);
        }
    }
    {
        float* op = out + xbase;
        #pragma unroll
        for (int nt = 0; nt < 24; ++nt) {
            const float pb = proj_b[nt * 16 + l15];
            #pragma unroll
            for (int reg = 0; reg < 4; ++reg) {
                const int i = wv * 16 + l4 * 4 + reg;
                if (i < NTOK) op[i * DIMC + nt * 16 + l15] = pacc[nt][reg] + pb;
            }
        }
    }
}

extern "C" void kernel_launch(void* const* d_in, const int* in_sizes, int n_in,
                              void* d_out, int out_size, void* d_ws, size_t ws_size,
                              hipStream_t stream) {
    const float* x          = (const float*)d_in[0];
    const float* mask       = (const float*)d_in[1];
    const float* qkv_w      = (const float*)d_in[2];
    const float* qkv_b      = (const float*)d_in[3];
    const float* proj_w     = (const float*)d_in[4];
    const float* proj_b     = (const float*)d_in[5];
    const float* bias_table = (const float*)d_in[6];
    float* out = (float*)d_out;

    const size_t need = (size_t)WQB_SHORTS * 2 + (size_t)WPB_SHORTS * 2 + AV_BYTES;
    if (ws_size >= need) {
        short* wqb = (short*)d_ws;
        short* wpb = wqb + WQB_SHORTS;
        char*  avb = (char*)(wpb + WPB_SHORTS);
        prep_weights<<<288, 256, 0, stream>>>(qkv_w, proj_w, wqb, wpb);
        winattn_fused<<<4096, 256, 0, stream>>>(x, mask, qkv_b, bias_table, wqb, avb);
        proj_gemm<<<MB_TILES * 3, 256, 0, stream>>>(avb, wpb, proj_b, out);
    } else {
        winattn_fallback<<<4096, 256, 0, stream>>>(x, mask, qkv_w, qkv_b, proj_w,
                                                   proj_b, bias_table, out);
    }
}